// Round 1
// baseline (4143.528 us; speedup 1.0000x reference)
//
#include <hip/hip_runtime.h>
#include <math.h>

#define KG_E  50000
#define KG_R  500
#define E_DIM 300
#define CAP   1024
#define LRELU 0.2f
#define GM_BM 32

// ---------------- compaction of r_head / r_tail into nonzero lists ----------
__global__ __launch_bounds__(256) void k_compact(
    const float* __restrict__ rmat, const float* __restrict__ be,
    int* __restrict__ lidx, float* __restrict__ lsval,
    int* __restrict__ cnt, float* __restrict__ inv, int mslot)
{
  int r = blockIdx.x;
  const float* rowp = rmat + (size_t)r * KG_E;
  __shared__ int scnt;
  __shared__ float sred[256];
  int tid = threadIdx.x;
  if (tid == 0) scnt = 0;
  __syncthreads();
  float ls = 0.f;
  int*   li = lidx  + (size_t)(mslot*KG_R + r) * CAP;
  float* lv = lsval + (size_t)(mslot*KG_R + r) * CAP;
  for (int e = tid; e < KG_E; e += 256) {
    float v = rowp[e];
    if (v != 0.f) {
      ls += v;
      int pos = atomicAdd(&scnt, 1);
      if (pos < CAP) { li[pos] = e; lv[pos] = v * be[e]; }
    }
  }
  sred[tid] = ls;
  __syncthreads();
  for (int s = 128; s > 0; s >>= 1) { if (tid < s) sred[tid] += sred[tid + s]; __syncthreads(); }
  if (tid == 0) {
    cnt[mslot*KG_R + r] = scnt > CAP ? CAP : scnt;
    float s = sred[0];
    inv[mslot*KG_R + r] = (s == 0.f) ? 0.f : 1.f / s;
  }
}

// ---------------- r-layer: w[m][r][d] = relu(inv * sum sval*E[e,d]) * atten -
__global__ __launch_bounds__(320) void k_rlayer(
    const float* __restrict__ E, const int* __restrict__ lidx,
    const float* __restrict__ lsval, const int* __restrict__ cnt,
    const float* __restrict__ inv, const float* __restrict__ atten,
    float* __restrict__ w)
{
  int b = blockIdx.x;           // 0..2*KG_R-1
  int m = b / KG_R, r = b % KG_R;
  int d = threadIdx.x;
  if (d >= E_DIM) return;
  int n = cnt[m*KG_R + r];
  const int*   li = lidx  + (size_t)(m*KG_R + r) * CAP;
  const float* lv = lsval + (size_t)(m*KG_R + r) * CAP;
  float acc = 0.f;
  #pragma unroll 4
  for (int i = 0; i < n; ++i) {
    int e = li[i];
    float s = lv[i];
    acc += s * E[(size_t)e * E_DIM + d];
  }
  float v = acc * inv[m*KG_R + r];
  v = v > 0.f ? v : 0.f;
  w[(size_t)(m*KG_R + r) * E_DIM + d] = v * atten[m*E_DIM + d];
}

// ---------------- attention edges: one wave per edge -----------------------
__global__ __launch_bounds__(256) void k_att(
    const float* __restrict__ E, const float* __restrict__ w,
    const int* __restrict__ eidx, const int* __restrict__ erel,
    float* __restrict__ acc, float* __restrict__ rowsum, int neer)
{
  int wave = threadIdx.x >> 6, lane = threadIdx.x & 63;
  int m = blockIdx.x * 4 + wave;
  if (m >= neer) return;
  int row = eidx[m];
  int col = eidx[neer + m];
  int rel = erel[m];
  const float* er = E + (size_t)row * E_DIM;
  const float* ec = E + (size_t)col * E_DIM;
  const float* wh = w + (size_t)rel * E_DIM;
  const float* wt = w + (size_t)KG_R * E_DIM + (size_t)rel * E_DIM;
  float ecv[5];
  float p = 0.f;
  #pragma unroll
  for (int c = 0; c < 5; ++c) {
    int d = lane + c * 64;
    if (d < E_DIM) {
      float a = er[d], b = ec[d];
      ecv[c] = b;
      p += a * wh[d] + b * wt[d];
    } else ecv[c] = 0.f;
  }
  #pragma unroll
  for (int off = 32; off > 0; off >>= 1) p += __shfl_xor(p, off, 64);
  float la = p >= 0.f ? p : LRELU * p;
  float at = __expf(-la);
  if (lane == 0) atomicAdd(rowsum + row, at);
  float* ap = acc + (size_t)row * E_DIM;
  #pragma unroll
  for (int c = 0; c < 5; ++c) {
    int d = lane + c * 64;
    if (d < E_DIM) atomicAdd(ap + d, at * ecv[c]);
  }
}

// ---------------- finalize: out = base + alpha*relu(acc*inv(rowsum)) -------
__global__ __launch_bounds__(320) void k_finalize(
    const float* __restrict__ base, const float* __restrict__ acc,
    const float* __restrict__ rowsum, float alpha, float* __restrict__ out)
{
  int r = blockIdx.x, d = threadIdx.x;
  if (d >= E_DIM) return;
  float rs = rowsum[r];
  float iv = (rs == 0.f) ? 0.f : 1.f / rs;
  size_t i = (size_t)r * E_DIM + d;
  float v = acc[i] * iv;
  v = v > 0.f ? v : 0.f;
  out[i] = base[i] + alpha * v;
}

// ---------------- GEMM: Y[M,300] = X[M,300] @ W[300,300] -------------------
__global__ __launch_bounds__(320) void k_gemm(
    const float* __restrict__ X, const float* __restrict__ W,
    float* __restrict__ Y, int M)
{
  __shared__ float As[GM_BM][E_DIM];
  int r0 = blockIdx.x * GM_BM;
  int tid = threadIdx.x;
  // stage A tile (rows beyond M -> 0)
  for (int t = tid; t < GM_BM * (E_DIM / 4); t += 320) {
    int i = t / (E_DIM / 4), f = t % (E_DIM / 4);
    float4 v = make_float4(0.f, 0.f, 0.f, 0.f);
    if (r0 + i < M) v = ((const float4*)(X + (size_t)(r0 + i) * E_DIM))[f];
    ((float4*)&As[i][0])[f] = v;
  }
  __syncthreads();
  if (tid < E_DIM) {
    float accv[GM_BM];
    #pragma unroll
    for (int i = 0; i < GM_BM; ++i) accv[i] = 0.f;
    for (int k = 0; k < E_DIM; k += 4) {
      float w0 = W[(k + 0) * E_DIM + tid];
      float w1 = W[(k + 1) * E_DIM + tid];
      float w2 = W[(k + 2) * E_DIM + tid];
      float w3 = W[(k + 3) * E_DIM + tid];
      #pragma unroll
      for (int i = 0; i < GM_BM; ++i) {
        float4 a = *(const float4*)&As[i][k];
        accv[i] += a.x * w0 + a.y * w1 + a.z * w2 + a.w * w3;
      }
    }
    for (int i = 0; i < GM_BM; ++i)
      if (r0 + i < M) Y[(size_t)(r0 + i) * E_DIM + tid] = accv[i];
  }
}

// ---------------- spmm: Y[row] += data * X[col], one wave per edge ---------
__global__ __launch_bounds__(256) void k_spmm(
    const float* __restrict__ X, const int* __restrict__ aidx,
    const float* __restrict__ adata, float* __restrict__ Y, int ne)
{
  int wave = threadIdx.x >> 6, lane = threadIdx.x & 63;
  int m = blockIdx.x * 4 + wave;
  if (m >= ne) return;
  int row = aidx[m], col = aidx[ne + m];
  float v = adata[m];
  const float* xp = X + (size_t)col * E_DIM;
  float* yp = Y + (size_t)row * E_DIM;
  #pragma unroll
  for (int c = 0; c < 5; ++c) {
    int d = lane + c * 64;
    if (d < E_DIM) atomicAdd(yp + d, v * xp[d]);
  }
}

// ---------------- highway: out = sig(gl+br)*relu(y) + (1-sig)*base ---------
__global__ __launch_bounds__(320) void k_highway(
    const float* __restrict__ base, const float* __restrict__ y,
    const float* __restrict__ gateLin, const float* __restrict__ br,
    float* __restrict__ out)
{
  int r = blockIdx.x, d = threadIdx.x;
  if (d >= E_DIM) return;
  size_t i = (size_t)r * E_DIM + d;
  float g = 1.f / (1.f + __expf(-(gateLin[i] + br[d])));
  float yy = y[i]; yy = yy > 0.f ? yy : 0.f;
  float b = base[i];
  out[i] = g * yy + (1.f - g) * b;
}

extern "C" void kernel_launch(void* const* d_in, const int* in_sizes, int n_in,
                              void* d_out, int out_size, void* d_ws, size_t ws_size,
                              hipStream_t stream)
{
  const float* primal      = (const float*)d_in[0];
  const float* r_head      = (const float*)d_in[1];
  const float* r_tail      = (const float*)d_in[2];
  const float* e_adj_data  = (const float*)d_in[3];
  const float* be_L        = (const float*)d_in[4];
  const float* be_R        = (const float*)d_in[5];
  const float* atten_r     = (const float*)d_in[6];
  const float* gcnW1       = (const float*)d_in[7];
  const float* hwWr        = (const float*)d_in[8];
  const float* hwbr        = (const float*)d_in[9];
  const int*   e_adj_index = (const int*)d_in[10];
  const int*   eer_idx     = (const int*)d_in[11];
  const int*   eer_rel     = (const int*)d_in[12];
  int ne   = in_sizes[10] / 2;
  int neer = in_sizes[11] / 2;

  char* ws = (char*)d_ws;
  size_t off = 0;
  auto take = [&](size_t bytes) {
    void* p = ws + off;
    off = (off + bytes + 255) & ~(size_t)255;
    return p;
  };
  int*   cnt    = (int*)  take((size_t)2 * KG_R * sizeof(int));
  float* inv    = (float*)take((size_t)2 * KG_R * sizeof(float));
  int*   lidx   = (int*)  take((size_t)2 * KG_R * CAP * sizeof(int));
  float* lsv    = (float*)take((size_t)2 * KG_R * CAP * sizeof(float));
  float* wbuf   = (float*)take((size_t)2 * KG_R * E_DIM * sizeof(float));
  float* rowsum = (float*)take((size_t)KG_E * sizeof(float));
  float* D      = (float*)take((size_t)KG_E * E_DIM * sizeof(float));
  float* E      = (float*)take((size_t)KG_E * E_DIM * sizeof(float));
  float* F      = (float*)take((size_t)KG_E * E_DIM * sizeof(float));
  float* out    = (float*)d_out;
  (void)ws_size; (void)n_in; (void)out_size;

  const size_t EMB_BYTES = (size_t)KG_E * E_DIM * sizeof(float);

  // compact r_head/r_tail (values folded with be_L/be_R); also rh_inv/rt_inv
  k_compact<<<KG_R, 256, 0, stream>>>(r_head, be_L, lidx, lsv, cnt, inv, 0);
  k_compact<<<KG_R, 256, 0, stream>>>(r_tail, be_R, lidx, lsv, cnt, inv, 1);

  // ---- attention layer 1 (base = primal, alpha = 0.1) ----
  hipMemsetAsync(D, 0, EMB_BYTES, stream);
  hipMemsetAsync(rowsum, 0, (size_t)KG_E * sizeof(float), stream);
  k_rlayer<<<2 * KG_R, 320, 0, stream>>>(primal, lidx, lsv, cnt, inv, atten_r, wbuf);
  k_att<<<(neer + 3) / 4, 256, 0, stream>>>(primal, wbuf, eer_idx, eer_rel, D, rowsum, neer);
  k_finalize<<<KG_E, 320, 0, stream>>>(primal, D, rowsum, 0.1f, E);   // e1

  // ---- attention layer 2 (base = primal, alpha = 0.3) ----
  hipMemsetAsync(D, 0, EMB_BYTES, stream);
  hipMemsetAsync(rowsum, 0, (size_t)KG_E * sizeof(float), stream);
  k_rlayer<<<2 * KG_R, 320, 0, stream>>>(E, lidx, lsv, cnt, inv, atten_r, wbuf);
  k_att<<<(neer + 3) / 4, 256, 0, stream>>>(E, wbuf, eer_idx, eer_rel, D, rowsum, neer);
  k_finalize<<<KG_E, 320, 0, stream>>>(primal, D, rowsum, 0.3f, E);   // e2

  // ---- GCN + highway 1 ----
  int gemm_grid = (KG_E + GM_BM - 1) / GM_BM;
  k_gemm<<<gemm_grid, 320, 0, stream>>>(E, gcnW1, F, KG_E);           // e2 @ gcnW1
  hipMemsetAsync(out, 0, EMB_BYTES, stream);
  k_spmm<<<(ne + 3) / 4, 256, 0, stream>>>(F, e_adj_index, e_adj_data, out, ne); // y1
  k_gemm<<<gemm_grid, 320, 0, stream>>>(E, hwWr, F, KG_E);            // gateLin1
  k_highway<<<KG_E, 320, 0, stream>>>(E, out, F, hwbr, D);            // g2 -> D

  // ---- GCN + highway 2 ----
  k_gemm<<<gemm_grid, 320, 0, stream>>>(D, gcnW1, F, KG_E);           // g2 @ gcnW1
  hipMemsetAsync(out, 0, EMB_BYTES, stream);
  k_spmm<<<(ne + 3) / 4, 256, 0, stream>>>(F, e_adj_index, e_adj_data, out, ne); // y2
  k_gemm<<<gemm_grid, 320, 0, stream>>>(D, hwWr, F, KG_E);            // gateLin2
  k_highway<<<KG_E, 320, 0, stream>>>(D, out, F, hwbr, out);          // final
}

// Round 2
// 2829.310 us; speedup vs baseline: 1.4645x; 1.4645x over previous
//
#include <hip/hip_runtime.h>
#include <math.h>

#define KG_E  50000
#define KG_R  500
#define E_DIM 300
#define CAP   1024
#define LRELU 0.2f
#define GM_BM 32

// ---------------- compaction of r_head / r_tail into nonzero lists ----------
__global__ __launch_bounds__(256) void k_compact(
    const float* __restrict__ rmat, const float* __restrict__ be,
    int* __restrict__ lidx, float* __restrict__ lsval,
    int* __restrict__ cnt, float* __restrict__ inv, int mslot)
{
  int r = blockIdx.x;
  const float* rowp = rmat + (size_t)r * KG_E;
  __shared__ int scnt;
  __shared__ float sred[256];
  int tid = threadIdx.x;
  if (tid == 0) scnt = 0;
  __syncthreads();
  float ls = 0.f;
  int*   li = lidx  + (size_t)(mslot*KG_R + r) * CAP;
  float* lv = lsval + (size_t)(mslot*KG_R + r) * CAP;
  for (int e = tid; e < KG_E; e += 256) {
    float v = rowp[e];
    if (v != 0.f) {
      ls += v;
      int pos = atomicAdd(&scnt, 1);
      if (pos < CAP) { li[pos] = e; lv[pos] = v * be[e]; }
    }
  }
  sred[tid] = ls;
  __syncthreads();
  for (int s = 128; s > 0; s >>= 1) { if (tid < s) sred[tid] += sred[tid + s]; __syncthreads(); }
  if (tid == 0) {
    cnt[mslot*KG_R + r] = scnt > CAP ? CAP : scnt;
    float s = sred[0];
    inv[mslot*KG_R + r] = (s == 0.f) ? 0.f : 1.f / s;
  }
}

// ---------------- r-layer: w[m][r][d] = relu(inv * sum sval*E[e,d]) * atten -
__global__ __launch_bounds__(320) void k_rlayer(
    const float* __restrict__ E, const int* __restrict__ lidx,
    const float* __restrict__ lsval, const int* __restrict__ cnt,
    const float* __restrict__ inv, const float* __restrict__ atten,
    float* __restrict__ w)
{
  int b = blockIdx.x;           // 0..2*KG_R-1
  int m = b / KG_R, r = b % KG_R;
  int d = threadIdx.x;
  if (d >= E_DIM) return;
  int n = cnt[m*KG_R + r];
  const int*   li = lidx  + (size_t)(m*KG_R + r) * CAP;
  const float* lv = lsval + (size_t)(m*KG_R + r) * CAP;
  float acc = 0.f;
  #pragma unroll 4
  for (int i = 0; i < n; ++i) {
    int e = li[i];
    float s = lv[i];
    acc += s * E[(size_t)e * E_DIM + d];
  }
  float v = acc * inv[m*KG_R + r];
  v = v > 0.f ? v : 0.f;
  w[(size_t)(m*KG_R + r) * E_DIM + d] = v * atten[m*E_DIM + d];
}

// ---------------- CSR build: histogram, scan, scatter ----------------------
__global__ __launch_bounds__(256) void k_hist(
    const int* __restrict__ rows, int* __restrict__ cnt, int n)
{
  int i = blockIdx.x * 256 + threadIdx.x;
  if (i < n) atomicAdd(&cnt[rows[i]], 1);
}

// single-block exclusive scan over n entries (n ~ 50000), writes start[0..n]
__global__ __launch_bounds__(1024) void k_scan(
    const int* __restrict__ cnt, int* __restrict__ start, int n)
{
  __shared__ int buf[1024];
  __shared__ int carry;
  if (threadIdx.x == 0) carry = 0;
  __syncthreads();
  for (int base = 0; base < n; base += 1024) {
    int i = base + threadIdx.x;
    int v = (i < n) ? cnt[i] : 0;
    buf[threadIdx.x] = v;
    __syncthreads();
    for (int ofs = 1; ofs < 1024; ofs <<= 1) {
      int t = (threadIdx.x >= ofs) ? buf[threadIdx.x - ofs] : 0;
      __syncthreads();
      buf[threadIdx.x] += t;
      __syncthreads();
    }
    if (i < n) start[i] = carry + buf[threadIdx.x] - v;
    __syncthreads();
    if (threadIdx.x == 1023) carry += buf[1023];
    __syncthreads();
  }
  if (threadIdx.x == 0) start[n] = carry;
}

__global__ __launch_bounds__(256) void k_scatter_eer(
    const int* __restrict__ eidx, const int* __restrict__ erel,
    const int* __restrict__ start, int* __restrict__ fill,
    int* __restrict__ scol, int* __restrict__ srel, int neer)
{
  int i = blockIdx.x * 256 + threadIdx.x;
  if (i >= neer) return;
  int row = eidx[i];
  int pos = start[row] + atomicAdd(&fill[row], 1);
  scol[pos] = eidx[neer + i];
  srel[pos] = erel[i];
}

__global__ __launch_bounds__(256) void k_scatter_adj(
    const int* __restrict__ aidx, const float* __restrict__ adata,
    const int* __restrict__ start, int* __restrict__ fill,
    int* __restrict__ scol, float* __restrict__ sval, int ne)
{
  int i = blockIdx.x * 256 + threadIdx.x;
  if (i >= ne) return;
  int row = aidx[i];
  int pos = start[row] + atomicAdd(&fill[row], 1);
  scol[pos] = aidx[ne + i];
  sval[pos] = adata[i];
}

// ---------------- attention, CSR row-parallel, fused finalize --------------
// out[row] = base[row] + alpha * relu( (sum_j at_j * E[col_j]) / sum_j at_j )
__global__ __launch_bounds__(256) void k_att_csr(
    const float* __restrict__ E, const float* __restrict__ w,
    const int* __restrict__ start, const int* __restrict__ scol,
    const int* __restrict__ srel, const float* __restrict__ base,
    float alpha, float* __restrict__ out)
{
  int wave = threadIdx.x >> 6, lane = threadIdx.x & 63;
  int row = blockIdx.x * 4 + wave;
  if (row >= KG_E) return;
  int s = start[row], e = start[row + 1];
  float er[5], acc[5] = {0.f, 0.f, 0.f, 0.f, 0.f};
  #pragma unroll
  for (int c = 0; c < 5; ++c) {
    int d = lane + c * 64;
    er[c] = (d < E_DIM) ? E[(size_t)row * E_DIM + d] : 0.f;
  }
  float rs = 0.f;
  for (int j = s; j < e; ++j) {
    int col = scol[j], rel = srel[j];
    const float* ec = E + (size_t)col * E_DIM;
    const float* wh = w + (size_t)rel * E_DIM;
    const float* wt = w + (size_t)(KG_R + rel) * E_DIM;
    float ecv[5];
    float p = 0.f;
    #pragma unroll
    for (int c = 0; c < 5; ++c) {
      int d = lane + c * 64;
      if (d < E_DIM) {
        float b = ec[d];
        ecv[c] = b;
        p += er[c] * wh[d] + b * wt[d];
      } else ecv[c] = 0.f;
    }
    #pragma unroll
    for (int off = 32; off > 0; off >>= 1) p += __shfl_xor(p, off, 64);
    float la = p >= 0.f ? p : LRELU * p;
    float at = __expf(-la);
    rs += at;
    #pragma unroll
    for (int c = 0; c < 5; ++c) acc[c] += at * ecv[c];
  }
  float iv = (rs == 0.f) ? 0.f : 1.f / rs;
  #pragma unroll
  for (int c = 0; c < 5; ++c) {
    int d = lane + c * 64;
    if (d < E_DIM) {
      size_t i = (size_t)row * E_DIM + d;
      float v = acc[c] * iv;
      v = v > 0.f ? v : 0.f;
      out[i] = base[i] + alpha * v;
    }
  }
}

// ---------------- spmm CSR row-parallel: Y[row] = sum val*X[col] -----------
__global__ __launch_bounds__(256) void k_spmm_csr(
    const float* __restrict__ X, const int* __restrict__ start,
    const int* __restrict__ scol, const float* __restrict__ sval,
    float* __restrict__ Y)
{
  int wave = threadIdx.x >> 6, lane = threadIdx.x & 63;
  int row = blockIdx.x * 4 + wave;
  if (row >= KG_E) return;
  int s = start[row], e = start[row + 1];
  float acc[5] = {0.f, 0.f, 0.f, 0.f, 0.f};
  for (int j = s; j < e; ++j) {
    int col = scol[j];
    float v = sval[j];
    const float* xp = X + (size_t)col * E_DIM;
    #pragma unroll
    for (int c = 0; c < 5; ++c) {
      int d = lane + c * 64;
      if (d < E_DIM) acc[c] += v * xp[d];
    }
  }
  #pragma unroll
  for (int c = 0; c < 5; ++c) {
    int d = lane + c * 64;
    if (d < E_DIM) Y[(size_t)row * E_DIM + d] = acc[c];
  }
}

// ---------------- GEMM: Y[M,300] = X[M,300] @ W[300,300] -------------------
__global__ __launch_bounds__(320) void k_gemm(
    const float* __restrict__ X, const float* __restrict__ W,
    float* __restrict__ Y, int M)
{
  __shared__ float As[GM_BM][E_DIM];
  int r0 = blockIdx.x * GM_BM;
  int tid = threadIdx.x;
  for (int t = tid; t < GM_BM * (E_DIM / 4); t += 320) {
    int i = t / (E_DIM / 4), f = t % (E_DIM / 4);
    float4 v = make_float4(0.f, 0.f, 0.f, 0.f);
    if (r0 + i < M) v = ((const float4*)(X + (size_t)(r0 + i) * E_DIM))[f];
    ((float4*)&As[i][0])[f] = v;
  }
  __syncthreads();
  if (tid < E_DIM) {
    float accv[GM_BM];
    #pragma unroll
    for (int i = 0; i < GM_BM; ++i) accv[i] = 0.f;
    for (int k = 0; k < E_DIM; k += 4) {
      float w0 = W[(k + 0) * E_DIM + tid];
      float w1 = W[(k + 1) * E_DIM + tid];
      float w2 = W[(k + 2) * E_DIM + tid];
      float w3 = W[(k + 3) * E_DIM + tid];
      #pragma unroll
      for (int i = 0; i < GM_BM; ++i) {
        float4 a = *(const float4*)&As[i][k];
        accv[i] += a.x * w0 + a.y * w1 + a.z * w2 + a.w * w3;
      }
    }
    for (int i = 0; i < GM_BM; ++i)
      if (r0 + i < M) Y[(size_t)(r0 + i) * E_DIM + tid] = accv[i];
  }
}

// ---------------- highway: out = sig(gl+br)*relu(y) + (1-sig)*base ---------
__global__ __launch_bounds__(320) void k_highway(
    const float* __restrict__ base, const float* __restrict__ y,
    const float* __restrict__ gateLin, const float* __restrict__ br,
    float* __restrict__ out)
{
  int r = blockIdx.x, d = threadIdx.x;
  if (d >= E_DIM) return;
  size_t i = (size_t)r * E_DIM + d;
  float g = 1.f / (1.f + __expf(-(gateLin[i] + br[d])));
  float yy = y[i]; yy = yy > 0.f ? yy : 0.f;
  float b = base[i];
  out[i] = g * yy + (1.f - g) * b;
}

extern "C" void kernel_launch(void* const* d_in, const int* in_sizes, int n_in,
                              void* d_out, int out_size, void* d_ws, size_t ws_size,
                              hipStream_t stream)
{
  const float* primal      = (const float*)d_in[0];
  const float* r_head      = (const float*)d_in[1];
  const float* r_tail      = (const float*)d_in[2];
  const float* e_adj_data  = (const float*)d_in[3];
  const float* be_L        = (const float*)d_in[4];
  const float* be_R        = (const float*)d_in[5];
  const float* atten_r     = (const float*)d_in[6];
  const float* gcnW1       = (const float*)d_in[7];
  const float* hwWr        = (const float*)d_in[8];
  const float* hwbr        = (const float*)d_in[9];
  const int*   e_adj_index = (const int*)d_in[10];
  const int*   eer_idx     = (const int*)d_in[11];
  const int*   eer_rel     = (const int*)d_in[12];
  int ne   = in_sizes[10] / 2;
  int neer = in_sizes[11] / 2;

  char* ws = (char*)d_ws;
  size_t off = 0;
  auto take = [&](size_t bytes) {
    void* p = ws + off;
    off = (off + bytes + 255) & ~(size_t)255;
    return p;
  };
  int*   cnt      = (int*)  take((size_t)2 * KG_R * sizeof(int));
  float* inv      = (float*)take((size_t)2 * KG_R * sizeof(float));
  int*   lidx     = (int*)  take((size_t)2 * KG_R * CAP * sizeof(int));
  float* lsv      = (float*)take((size_t)2 * KG_R * CAP * sizeof(float));
  float* wbuf     = (float*)take((size_t)2 * KG_R * E_DIM * sizeof(float));
  int*   hcnt     = (int*)  take((size_t)KG_E * sizeof(int));        // histogram scratch
  int*   hfill    = (int*)  take((size_t)KG_E * sizeof(int));        // scatter fill
  int*   eer_start= (int*)  take((size_t)(KG_E + 1) * sizeof(int));
  int*   adj_start= (int*)  take((size_t)(KG_E + 1) * sizeof(int));
  int*   eer_scol = (int*)  take((size_t)neer * sizeof(int));
  int*   eer_srel = (int*)  take((size_t)neer * sizeof(int));
  int*   adj_scol = (int*)  take((size_t)ne * sizeof(int));
  float* adj_sval = (float*)take((size_t)ne * sizeof(float));
  float* D        = (float*)take((size_t)KG_E * E_DIM * sizeof(float));
  float* E        = (float*)take((size_t)KG_E * E_DIM * sizeof(float));
  float* F        = (float*)take((size_t)KG_E * E_DIM * sizeof(float));
  float* out      = (float*)d_out;
  (void)ws_size; (void)n_in; (void)out_size;

  int eg = (neer + 255) / 256;
  int ag = (ne + 255) / 256;

  // ---- build CSR for eer edges ----
  hipMemsetAsync(hcnt, 0, (size_t)KG_E * sizeof(int), stream);
  k_hist<<<eg, 256, 0, stream>>>(eer_idx, hcnt, neer);
  k_scan<<<1, 1024, 0, stream>>>(hcnt, eer_start, KG_E);
  hipMemsetAsync(hfill, 0, (size_t)KG_E * sizeof(int), stream);
  k_scatter_eer<<<eg, 256, 0, stream>>>(eer_idx, eer_rel, eer_start, hfill,
                                        eer_scol, eer_srel, neer);
  // ---- build CSR for e_adj edges ----
  hipMemsetAsync(hcnt, 0, (size_t)KG_E * sizeof(int), stream);
  k_hist<<<ag, 256, 0, stream>>>(e_adj_index, hcnt, ne);
  k_scan<<<1, 1024, 0, stream>>>(hcnt, adj_start, KG_E);
  hipMemsetAsync(hfill, 0, (size_t)KG_E * sizeof(int), stream);
  k_scatter_adj<<<ag, 256, 0, stream>>>(e_adj_index, e_adj_data, adj_start, hfill,
                                        adj_scol, adj_sval, ne);

  // ---- compact r_head/r_tail (values folded with be_L/be_R) + inv sums ----
  k_compact<<<KG_R, 256, 0, stream>>>(r_head, be_L, lidx, lsv, cnt, inv, 0);
  k_compact<<<KG_R, 256, 0, stream>>>(r_tail, be_R, lidx, lsv, cnt, inv, 1);

  int rg = (KG_E + 3) / 4;

  // ---- attention layer 1: e1 = primal + 0.1*att(primal) -> E ----
  k_rlayer<<<2 * KG_R, 320, 0, stream>>>(primal, lidx, lsv, cnt, inv, atten_r, wbuf);
  k_att_csr<<<rg, 256, 0, stream>>>(primal, wbuf, eer_start, eer_scol, eer_srel,
                                    primal, 0.1f, E);
  // ---- attention layer 2: e2 = primal + 0.3*att(e1) -> D ----
  k_rlayer<<<2 * KG_R, 320, 0, stream>>>(E, lidx, lsv, cnt, inv, atten_r, wbuf);
  k_att_csr<<<rg, 256, 0, stream>>>(E, wbuf, eer_start, eer_scol, eer_srel,
                                    primal, 0.3f, D);

  // ---- GCN + highway 1: g2 = highway(e2, relu(spmm(e2@gcnW1))) -> E ----
  int gemm_grid = (KG_E + GM_BM - 1) / GM_BM;
  k_gemm<<<gemm_grid, 320, 0, stream>>>(D, gcnW1, F, KG_E);
  k_spmm_csr<<<rg, 256, 0, stream>>>(F, adj_start, adj_scol, adj_sval, out);
  k_gemm<<<gemm_grid, 320, 0, stream>>>(D, hwWr, F, KG_E);
  k_highway<<<KG_E, 320, 0, stream>>>(D, out, F, hwbr, E);

  // ---- GCN + highway 2: out = highway(g2, relu(spmm(g2@gcnW1))) ----
  k_gemm<<<gemm_grid, 320, 0, stream>>>(E, gcnW1, F, KG_E);
  k_spmm_csr<<<rg, 256, 0, stream>>>(F, adj_start, adj_scol, adj_sval, out);
  k_gemm<<<gemm_grid, 320, 0, stream>>>(E, hwWr, F, KG_E);
  k_highway<<<KG_E, 320, 0, stream>>>(E, out, F, hwbr, out);
}

// Round 3
// 1403.376 us; speedup vs baseline: 2.9525x; 2.0161x over previous
//
#include <hip/hip_runtime.h>
#include <math.h>

#define KG_E  50000
#define KG_R  500
#define E_DIM 300
#define CAP   1024
#define LRELU 0.2f

// MFMA GEMM geometry: Y[M,600(pad 640)] = X[M,300(pad 320)] @ Wcat
#define NK    10          // K-steps of 32 (K padded 300->320)
#define NT    40          // 16-col n-tiles (600 -> 640)
#define XS_LD 328         // LDS row stride in bf16 (+8 pad)

typedef __attribute__((ext_vector_type(8))) short bf16x8;
typedef __attribute__((ext_vector_type(4))) float f32x4;

__device__ __forceinline__ unsigned short f2bf(float x) {
  union { float f; unsigned u; } v; v.f = x;
  unsigned r = v.u + 0x7FFFu + ((v.u >> 16) & 1u);
  return (unsigned short)(r >> 16);
}

// ---------------- compaction of r_head / r_tail into nonzero lists ----------
__global__ __launch_bounds__(256) void k_compact(
    const float* __restrict__ rmat, const float* __restrict__ be,
    int* __restrict__ lidx, float* __restrict__ lsval,
    int* __restrict__ cnt, float* __restrict__ inv, int mslot)
{
  int r = blockIdx.x;
  const float* rowp = rmat + (size_t)r * KG_E;
  __shared__ int scnt;
  __shared__ float sred[256];
  int tid = threadIdx.x;
  if (tid == 0) scnt = 0;
  __syncthreads();
  float ls = 0.f;
  int*   li = lidx  + (size_t)(mslot*KG_R + r) * CAP;
  float* lv = lsval + (size_t)(mslot*KG_R + r) * CAP;
  for (int e = tid; e < KG_E; e += 256) {
    float v = rowp[e];
    if (v != 0.f) {
      ls += v;
      int pos = atomicAdd(&scnt, 1);
      if (pos < CAP) { li[pos] = e; lv[pos] = v * be[e]; }
    }
  }
  sred[tid] = ls;
  __syncthreads();
  for (int s = 128; s > 0; s >>= 1) { if (tid < s) sred[tid] += sred[tid + s]; __syncthreads(); }
  if (tid == 0) {
    cnt[mslot*KG_R + r] = scnt > CAP ? CAP : scnt;
    float s = sred[0];
    inv[mslot*KG_R + r] = (s == 0.f) ? 0.f : 1.f / s;
  }
}

// ---------------- r-layer: w[m][r][d] = relu(inv * sum sval*E[e,d]) * atten -
__global__ __launch_bounds__(320) void k_rlayer(
    const float* __restrict__ E, const int* __restrict__ lidx,
    const float* __restrict__ lsval, const int* __restrict__ cnt,
    const float* __restrict__ inv, const float* __restrict__ atten,
    float* __restrict__ w)
{
  int b = blockIdx.x;           // 0..2*KG_R-1
  int m = b / KG_R, r = b % KG_R;
  int d = threadIdx.x;
  if (d >= E_DIM) return;
  int n = cnt[m*KG_R + r];
  const int*   li = lidx  + (size_t)(m*KG_R + r) * CAP;
  const float* lv = lsval + (size_t)(m*KG_R + r) * CAP;
  float acc = 0.f;
  #pragma unroll 4
  for (int i = 0; i < n; ++i) {
    int e = li[i];
    float s = lv[i];
    acc += s * E[(size_t)e * E_DIM + d];
  }
  float v = acc * inv[m*KG_R + r];
  v = v > 0.f ? v : 0.f;
  w[(size_t)(m*KG_R + r) * E_DIM + d] = v * atten[m*E_DIM + d];
}

// ---------------- CSR build: histogram, scan, scatter ----------------------
__global__ __launch_bounds__(256) void k_hist(
    const int* __restrict__ rows, int* __restrict__ cnt, int n)
{
  int i = blockIdx.x * 256 + threadIdx.x;
  if (i < n) atomicAdd(&cnt[rows[i]], 1);
}

__global__ __launch_bounds__(1024) void k_scan(
    const int* __restrict__ cnt, int* __restrict__ start, int n)
{
  __shared__ int buf[1024];
  __shared__ int carry;
  if (threadIdx.x == 0) carry = 0;
  __syncthreads();
  for (int base = 0; base < n; base += 1024) {
    int i = base + threadIdx.x;
    int v = (i < n) ? cnt[i] : 0;
    buf[threadIdx.x] = v;
    __syncthreads();
    for (int ofs = 1; ofs < 1024; ofs <<= 1) {
      int t = (threadIdx.x >= ofs) ? buf[threadIdx.x - ofs] : 0;
      __syncthreads();
      buf[threadIdx.x] += t;
      __syncthreads();
    }
    if (i < n) start[i] = carry + buf[threadIdx.x] - v;
    __syncthreads();
    if (threadIdx.x == 1023) carry += buf[1023];
    __syncthreads();
  }
  if (threadIdx.x == 0) start[n] = carry;
}

__global__ __launch_bounds__(256) void k_scatter_eer(
    const int* __restrict__ eidx, const int* __restrict__ erel,
    const int* __restrict__ start, int* __restrict__ fill,
    int* __restrict__ scol, int* __restrict__ srel, int neer)
{
  int i = blockIdx.x * 256 + threadIdx.x;
  if (i >= neer) return;
  int row = eidx[i];
  int pos = start[row] + atomicAdd(&fill[row], 1);
  scol[pos] = eidx[neer + i];
  srel[pos] = erel[i];
}

__global__ __launch_bounds__(256) void k_scatter_adj(
    const int* __restrict__ aidx, const float* __restrict__ adata,
    const int* __restrict__ start, int* __restrict__ fill,
    int* __restrict__ scol, float* __restrict__ sval, int ne)
{
  int i = blockIdx.x * 256 + threadIdx.x;
  if (i >= ne) return;
  int row = aidx[i];
  int pos = start[row] + atomicAdd(&fill[row], 1);
  scol[pos] = aidx[ne + i];
  sval[pos] = adata[i];
}

// ---------------- attention, CSR row-parallel, fused finalize --------------
// out[row] = base[row] + alpha * relu( (sum at_j * E[col_j]) / sum at_j )
// optionally also writes bf16 copy of out
__global__ __launch_bounds__(256) void k_att_csr(
    const float* __restrict__ E, const float* __restrict__ w,
    const int* __restrict__ start, const int* __restrict__ scol,
    const int* __restrict__ srel, const float* __restrict__ base,
    float alpha, float* __restrict__ out, unsigned short* __restrict__ outb)
{
  int wave = threadIdx.x >> 6, lane = threadIdx.x & 63;
  int row = blockIdx.x * 4 + wave;
  if (row >= KG_E) return;
  int s = start[row], e = start[row + 1];
  float er[5], acc[5] = {0.f, 0.f, 0.f, 0.f, 0.f};
  #pragma unroll
  for (int c = 0; c < 5; ++c) {
    int d = lane + c * 64;
    er[c] = (d < E_DIM) ? E[(size_t)row * E_DIM + d] : 0.f;
  }
  float rs = 0.f;
  for (int j = s; j < e; ++j) {
    int col = scol[j], rel = srel[j];
    const float* ec = E + (size_t)col * E_DIM;
    const float* wh = w + (size_t)rel * E_DIM;
    const float* wt = w + (size_t)(KG_R + rel) * E_DIM;
    float ecv[5];
    float p = 0.f;
    #pragma unroll
    for (int c = 0; c < 5; ++c) {
      int d = lane + c * 64;
      if (d < E_DIM) {
        float b = ec[d];
        ecv[c] = b;
        p += er[c] * wh[d] + b * wt[d];
      } else ecv[c] = 0.f;
    }
    #pragma unroll
    for (int off = 32; off > 0; off >>= 1) p += __shfl_xor(p, off, 64);
    float la = p >= 0.f ? p : LRELU * p;
    float at = __expf(-la);
    rs += at;
    #pragma unroll
    for (int c = 0; c < 5; ++c) acc[c] += at * ecv[c];
  }
  float iv = (rs == 0.f) ? 0.f : 1.f / rs;
  #pragma unroll
  for (int c = 0; c < 5; ++c) {
    int d = lane + c * 64;
    if (d < E_DIM) {
      size_t i = (size_t)row * E_DIM + d;
      float v = acc[c] * iv;
      v = v > 0.f ? v : 0.f;
      float o = base[i] + alpha * v;
      out[i] = o;
      if (outb) outb[i] = f2bf(o);
    }
  }
}

// ---------------- spmm CSR row-parallel: Y[row] = sum val*X[col] -----------
__global__ __launch_bounds__(256) void k_spmm_csr(
    const float* __restrict__ X, const int* __restrict__ start,
    const int* __restrict__ scol, const float* __restrict__ sval,
    float* __restrict__ Y)
{
  int wave = threadIdx.x >> 6, lane = threadIdx.x & 63;
  int row = blockIdx.x * 4 + wave;
  if (row >= KG_E) return;
  int s = start[row], e = start[row + 1];
  float acc[5] = {0.f, 0.f, 0.f, 0.f, 0.f};
  for (int j = s; j < e; ++j) {
    int col = scol[j];
    float v = sval[j];
    const float* xp = X + (size_t)col * E_DIM;
    #pragma unroll
    for (int c = 0; c < 5; ++c) {
      int d = lane + c * 64;
      if (d < E_DIM) acc[c] += v * xp[d];
    }
  }
  #pragma unroll
  for (int c = 0; c < 5; ++c) {
    int d = lane + c * 64;
    if (d < E_DIM) Y[(size_t)row * E_DIM + d] = acc[c];
  }
}

// ---------------- pack W into MFMA B-fragment layout -----------------------
// Wp frag idx: ((tile*NK + ks)*64 + lane)*8 + j  holds  B[k][c],
//   k = ks*32 + (lane/16)*8 + j,  c = tile*16 + lane%16
//   c<300 -> gcnW1[k][c]; 300<=c<600 -> hwWr[k][c-300]; else 0
__global__ __launch_bounds__(64) void k_packW(
    const float* __restrict__ W1, const float* __restrict__ W2,
    unsigned short* __restrict__ Wp)
{
  int lane = threadIdx.x;
  int t = blockIdx.x, s = blockIdx.y;
  int c = t * 16 + (lane & 15);
  unsigned short v[8];
  #pragma unroll
  for (int j = 0; j < 8; ++j) {
    int k = s * 32 + (lane >> 4) * 8 + j;
    float x = 0.f;
    if (k < E_DIM && c < 2 * E_DIM)
      x = (c < E_DIM) ? W1[(size_t)k * E_DIM + c]
                      : W2[(size_t)k * E_DIM + (c - E_DIM)];
    v[j] = f2bf(x);
  }
  size_t base = ((size_t)(t * NK + s) * 64 + lane) * 8;
  #pragma unroll
  for (int j = 0; j < 8; ++j) Wp[base + j] = v[j];
}

// ---------------- fused dual-GEMM: {Y1,Y2} = Xb @ {gcnW1,hwWr} (bf16 MFMA) -
// block: 256 thr = 4 waves (2M x 2N); tile BM=32, BN=128; full K in LDS
__global__ __launch_bounds__(256) void k_gemm2_mfma(
    const unsigned short* __restrict__ Xb, const unsigned short* __restrict__ Wp,
    float* __restrict__ Y1, float* __restrict__ Y2, int M)
{
  __shared__ unsigned short Xs[32][XS_LD];
  int tid = threadIdx.x;
  int r0 = blockIdx.x * 32;
  int nb = blockIdx.y;               // 0..4, 128 cols each

  // stage X tile: rows r0..r0+31, k 0..319 (pad 300..319 with 0)
  for (int t = tid; t < 32 * (XS_LD / 2); t += 256) {
    int r = t / (XS_LD / 2), u = t % (XS_LD / 2);
    unsigned v = 0;
    int rg = r0 + r;
    if (rg < M && u < E_DIM / 2) v = ((const unsigned*)Xb)[(size_t)rg * (E_DIM / 2) + u];
    ((unsigned*)&Xs[0][0])[r * (XS_LD / 2) + u] = v;
  }
  __syncthreads();

  int wid = tid >> 6, lane = tid & 63;
  int wave_m = wid >> 1, wave_n = wid & 1;
  int rowA = wave_m * 16 + (lane & 15);
  int kgrp = (lane >> 4) * 8;
  int tb0 = nb * 8 + wave_n * 4;     // first of 4 n-tiles for this wave

  const bf16x8* wfrag = (const bf16x8*)Wp + (size_t)tb0 * (NK * 64) + lane;

  f32x4 acc[4] = {{0,0,0,0},{0,0,0,0},{0,0,0,0},{0,0,0,0}};
  #pragma unroll 2
  for (int ks = 0; ks < NK; ++ks) {
    bf16x8 a = *(const bf16x8*)&Xs[rowA][ks * 32 + kgrp];
    #pragma unroll
    for (int nt = 0; nt < 4; ++nt) {
      bf16x8 b = wfrag[(nt * NK + ks) * 64];
      acc[nt] = __builtin_amdgcn_mfma_f32_16x16x32_bf16(a, b, acc[nt], 0, 0, 0);
    }
  }

  int rbase = r0 + wave_m * 16 + ((lane >> 4) << 2);
  #pragma unroll
  for (int nt = 0; nt < 4; ++nt) {
    int c = (tb0 + nt) * 16 + (lane & 15);
    #pragma unroll
    for (int j = 0; j < 4; ++j) {
      int row = rbase + j;
      if (row < M) {
        float v = acc[nt][j];
        if (c < E_DIM)            Y1[(size_t)row * E_DIM + c] = v;
        else if (c < 2 * E_DIM)   Y2[(size_t)row * E_DIM + (c - E_DIM)] = v;
      }
    }
  }
}

// ---------------- highway: out = sig(gl+br)*relu(y) + (1-sig)*base ---------
__global__ __launch_bounds__(320) void k_highway(
    const float* __restrict__ base, const float* __restrict__ y,
    const float* __restrict__ gateLin, const float* __restrict__ br,
    float* __restrict__ out, unsigned short* __restrict__ outb)
{
  int r = blockIdx.x, d = threadIdx.x;
  if (d >= E_DIM) return;
  size_t i = (size_t)r * E_DIM + d;
  float g = 1.f / (1.f + __expf(-(gateLin[i] + br[d])));
  float yy = y[i]; yy = yy > 0.f ? yy : 0.f;
  float b = base[i];
  float o = g * yy + (1.f - g) * b;
  out[i] = o;
  if (outb) outb[i] = f2bf(o);
}

extern "C" void kernel_launch(void* const* d_in, const int* in_sizes, int n_in,
                              void* d_out, int out_size, void* d_ws, size_t ws_size,
                              hipStream_t stream)
{
  const float* primal      = (const float*)d_in[0];
  const float* r_head      = (const float*)d_in[1];
  const float* r_tail      = (const float*)d_in[2];
  const float* e_adj_data  = (const float*)d_in[3];
  const float* be_L        = (const float*)d_in[4];
  const float* be_R        = (const float*)d_in[5];
  const float* atten_r     = (const float*)d_in[6];
  const float* gcnW1       = (const float*)d_in[7];
  const float* hwWr        = (const float*)d_in[8];
  const float* hwbr        = (const float*)d_in[9];
  const int*   e_adj_index = (const int*)d_in[10];
  const int*   eer_idx     = (const int*)d_in[11];
  const int*   eer_rel     = (const int*)d_in[12];
  int ne   = in_sizes[10] / 2;
  int neer = in_sizes[11] / 2;

  char* ws = (char*)d_ws;
  size_t off = 0;
  auto take = [&](size_t bytes) {
    void* p = ws + off;
    off = (off + bytes + 255) & ~(size_t)255;
    return p;
  };
  int*   cnt      = (int*)  take((size_t)2 * KG_R * sizeof(int));
  float* inv      = (float*)take((size_t)2 * KG_R * sizeof(float));
  int*   lidx     = (int*)  take((size_t)2 * KG_R * CAP * sizeof(int));
  float* lsv      = (float*)take((size_t)2 * KG_R * CAP * sizeof(float));
  float* wbuf     = (float*)take((size_t)2 * KG_R * E_DIM * sizeof(float));
  int*   hcnt     = (int*)  take((size_t)KG_E * sizeof(int));
  int*   hfill    = (int*)  take((size_t)KG_E * sizeof(int));
  int*   eer_start= (int*)  take((size_t)(KG_E + 1) * sizeof(int));
  int*   adj_start= (int*)  take((size_t)(KG_E + 1) * sizeof(int));
  int*   eer_scol = (int*)  take((size_t)neer * sizeof(int));
  int*   eer_srel = (int*)  take((size_t)neer * sizeof(int));
  int*   adj_scol = (int*)  take((size_t)ne * sizeof(int));
  float* adj_sval = (float*)take((size_t)ne * sizeof(float));
  unsigned short* Wp = (unsigned short*)take((size_t)NT * NK * 64 * 8 * sizeof(unsigned short));
  unsigned short* Xbf= (unsigned short*)take((size_t)KG_E * E_DIM * sizeof(unsigned short));
  float* D        = (float*)take((size_t)KG_E * E_DIM * sizeof(float));
  float* E        = (float*)take((size_t)KG_E * E_DIM * sizeof(float));
  float* F        = (float*)take((size_t)KG_E * E_DIM * sizeof(float));
  float* G        = (float*)take((size_t)KG_E * E_DIM * sizeof(float));
  float* out      = (float*)d_out;
  (void)ws_size; (void)n_in; (void)out_size;

  int eg = (neer + 255) / 256;
  int ag = (ne + 255) / 256;

  // ---- build CSR for eer edges ----
  hipMemsetAsync(hcnt, 0, (size_t)KG_E * sizeof(int), stream);
  k_hist<<<eg, 256, 0, stream>>>(eer_idx, hcnt, neer);
  k_scan<<<1, 1024, 0, stream>>>(hcnt, eer_start, KG_E);
  hipMemsetAsync(hfill, 0, (size_t)KG_E * sizeof(int), stream);
  k_scatter_eer<<<eg, 256, 0, stream>>>(eer_idx, eer_rel, eer_start, hfill,
                                        eer_scol, eer_srel, neer);
  // ---- build CSR for e_adj edges ----
  hipMemsetAsync(hcnt, 0, (size_t)KG_E * sizeof(int), stream);
  k_hist<<<ag, 256, 0, stream>>>(e_adj_index, hcnt, ne);
  k_scan<<<1, 1024, 0, stream>>>(hcnt, adj_start, KG_E);
  hipMemsetAsync(hfill, 0, (size_t)KG_E * sizeof(int), stream);
  k_scatter_adj<<<ag, 256, 0, stream>>>(e_adj_index, e_adj_data, adj_start, hfill,
                                        adj_scol, adj_sval, ne);

  // ---- compact r_head/r_tail + pack weights ----
  k_compact<<<KG_R, 256, 0, stream>>>(r_head, be_L, lidx, lsv, cnt, inv, 0);
  k_compact<<<KG_R, 256, 0, stream>>>(r_tail, be_R, lidx, lsv, cnt, inv, 1);
  k_packW<<<dim3(NT, NK), 64, 0, stream>>>(gcnW1, hwWr, Wp);

  int rg = (KG_E + 3) / 4;

  // ---- attention layer 1: e1 = primal + 0.1*att(primal) -> E ----
  k_rlayer<<<2 * KG_R, 320, 0, stream>>>(primal, lidx, lsv, cnt, inv, atten_r, wbuf);
  k_att_csr<<<rg, 256, 0, stream>>>(primal, wbuf, eer_start, eer_scol, eer_srel,
                                    primal, 0.1f, E, (unsigned short*)nullptr);
  // ---- attention layer 2: e2 = primal + 0.3*att(e1) -> D (+ bf16 Xbf) ----
  k_rlayer<<<2 * KG_R, 320, 0, stream>>>(E, lidx, lsv, cnt, inv, atten_r, wbuf);
  k_att_csr<<<rg, 256, 0, stream>>>(E, wbuf, eer_start, eer_scol, eer_srel,
                                    primal, 0.3f, D, Xbf);

  // ---- GCN + highway 1: F = e2@gcnW1, G = e2@hwWr; g2 -> E (+ bf16 Xbf) ----
  dim3 gg((KG_E + 31) / 32, 5);
  k_gemm2_mfma<<<gg, 256, 0, stream>>>(Xbf, Wp, F, G, KG_E);
  k_spmm_csr<<<rg, 256, 0, stream>>>(F, adj_start, adj_scol, adj_sval, out);
  k_highway<<<KG_E, 320, 0, stream>>>(D, out, G, hwbr, E, Xbf);

  // ---- GCN + highway 2: F = g2@gcnW1, G = g2@hwWr; out = highway ----
  k_gemm2_mfma<<<gg, 256, 0, stream>>>(Xbf, Wp, F, G, KG_E);
  k_spmm_csr<<<rg, 256, 0, stream>>>(F, adj_start, adj_scol, adj_sval, out);
  k_highway<<<KG_E, 320, 0, stream>>>(E, out, G, hwbr, out, (unsigned short*)nullptr);
}